// Round 1
// baseline (299.018 us; speedup 1.0000x reference)
//
#include <hip/hip_runtime.h>
#include <cstdint>
#include <cstddef>

// Problem constants
#define IMGW 640
#define HPW  160   // params spatial (640/4)
#define DCH  96
#define BATCH 2

// ---------------------------------------------------------------------------
// Kernel 1: fold embed (1x1 conv 3->96) into the 3x3 conv ph_w1.
//   W1f[e*27 + (ky*3+kx)*3 + c3] = sum_c96 ph_w1[e,c96,ky,kx] * embed_w[c96,c3]
//   B1f[e*9 + k]               = sum_c96 ph_w1[e,c96,k] * embed_b[c96]
//   bias_int[e]                = ph_b1[e] + sum_k B1f[e,k]   (all-taps-in-bounds bias)
// ---------------------------------------------------------------------------
__global__ void fold_kernel(const float* __restrict__ ph_w1,
                            const float* __restrict__ embed_w,
                            const float* __restrict__ embed_b,
                            const float* __restrict__ ph_b1,
                            float* __restrict__ W1f,
                            float* __restrict__ B1f,
                            float* __restrict__ bias_int) {
    int t = blockIdx.x * 256 + threadIdx.x;
    if (t < 2592) {
        int e = t / 27, r = t - e * 27;
        int k = r / 3, c3 = r - k * 3;
        float s = 0.f;
        for (int c = 0; c < 96; ++c)
            s += ph_w1[e * 864 + c * 9 + k] * embed_w[c * 3 + c3];
        W1f[t] = s;
    } else if (t < 3456) {
        int i = t - 2592;
        int e = i / 9, k = i - e * 9;
        float s = 0.f;
        for (int c = 0; c < 96; ++c)
            s += ph_w1[e * 864 + c * 9 + k] * embed_b[c];
        B1f[i] = s;
    } else if (t < 3552) {
        int e = t - 3456;
        float s = ph_b1[e];
        for (int c = 0; c < 96; ++c) {
            float bb = embed_b[c];
            const float* w = ph_w1 + e * 864 + c * 9;
            for (int k = 0; k < 9; ++k) s += w[k] * bb;
        }
        bias_int[e] = s;
    }
}

// ---------------------------------------------------------------------------
// Kernel 2: fused conv1(folded, K=27) + bias + exact GELU + conv2(4x4 stride 4)
// One block = 8x8 patches = 32x32 pixels. 256 threads, each owns a 2x2 pixel
// quad of one patch (64 patches * 4 threads).
// ---------------------------------------------------------------------------
__global__ __launch_bounds__(256) void params_kernel(
    const float* __restrict__ x,
    const float* __restrict__ W1f,
    const float* __restrict__ B1f,
    const float* __restrict__ bias_int,
    const float* __restrict__ ph_b1,
    const float* __restrict__ ph_w2,
    const float* __restrict__ ph_b2,
    float* __restrict__ params) {
    __shared__ float xs_l[3 * 34 * 34];   // x tile + 1px halo
    __shared__ float w1f_l[96 * 28];      // folded weights, padded 27->28 for b128
    __shared__ float w2_l[3 * 96 * 16];   // ph_w2 verbatim

    int bid = blockIdx.x;
    int b = bid / 400;
    int rem = bid - b * 400;
    int th = rem / 20, tw = rem - th * 20;
    int y0 = th * 32, x0 = tw * 32;
    int tid = threadIdx.x;

    const float* xb = x + (size_t)b * 3 * 409600;
    for (int l = tid; l < 3 * 34 * 34; l += 256) {
        int c = l / 1156;
        int r2 = l - c * 1156;
        int rr = r2 / 34, cc = r2 - rr * 34;
        int gy = y0 - 1 + rr, gx = x0 - 1 + cc;
        float v = 0.f;
        if (gy >= 0 && gy < IMGW && gx >= 0 && gx < IMGW)
            v = xb[c * 409600 + gy * 640 + gx];
        xs_l[l] = v;
    }
    for (int l = tid; l < 96 * 28; l += 256) {
        int e = l / 28, j = l - e * 28;
        w1f_l[l] = (j < 27) ? W1f[e * 27 + j] : 0.f;
    }
    for (int l = tid; l < 4608; l += 256) w2_l[l] = ph_w2[l];
    __syncthreads();

    int patch = tid >> 2, q = tid & 3;
    int pr = patch >> 3, pc = patch & 7;
    int qy = q >> 1, qx = q & 1;
    int ly0 = pr * 4 + qy * 2, lx0 = pc * 4 + qx * 2;

    // per-thread x window: rows ly0-1..ly0+2 -> halo idx ly0..ly0+3
    float xr[3][4][4];
#pragma unroll
    for (int c = 0; c < 3; ++c)
#pragma unroll
        for (int i = 0; i < 4; ++i)
#pragma unroll
            for (int j = 0; j < 4; ++j)
                xr[c][i][j] = xs_l[c * 1156 + (ly0 + i) * 34 + (lx0 + j)];

    bool border = (y0 == 0) || (x0 == 0) || (y0 == 608) || (x0 == 608);
    unsigned msk[2][2];
    if (border) {
#pragma unroll
        for (int a = 0; a < 2; ++a)
#pragma unroll
            for (int b2 = 0; b2 < 2; ++b2) {
                int gy = y0 + ly0 + a, gx = x0 + lx0 + b2;
                unsigned m = 0;
                for (int ky = 0; ky < 3; ++ky)
                    for (int kx = 0; kx < 3; ++kx) {
                        int iy = gy + ky - 1, ix = gx + kx - 1;
                        if (iy >= 0 && iy < IMGW && ix >= 0 && ix < IMGW)
                            m |= 1u << (ky * 3 + kx);
                    }
                msk[a][b2] = m;
            }
    }

    int pi00 = (qy * 2 + 0) * 4 + (qx * 2 + 0);
    int pi01 = pi00 + 1;
    int pi10 = pi00 + 4;
    int pi11 = pi00 + 5;

    float p0 = 0.f, p1 = 0.f, p2 = 0.f;

    for (int e = 0; e < 96; ++e) {
        float w[28];
        const float4* w4 = reinterpret_cast<const float4*>(&w1f_l[e * 28]);
#pragma unroll
        for (int t = 0; t < 7; ++t) {
            float4 v = w4[t];
            w[4 * t] = v.x; w[4 * t + 1] = v.y; w[4 * t + 2] = v.z; w[4 * t + 3] = v.w;
        }
        float base = bias_int[e];
        float acc[2][2] = {{base, base}, {base, base}};
        if (border) {
#pragma unroll
            for (int a = 0; a < 2; ++a)
#pragma unroll
                for (int b2 = 0; b2 < 2; ++b2) {
                    float bb = ph_b1[e];
                    unsigned m = msk[a][b2];
                    for (int k = 0; k < 9; ++k)
                        if ((m >> k) & 1u) bb += B1f[e * 9 + k];
                    acc[a][b2] = bb;
                }
        }
#pragma unroll
        for (int ky = 0; ky < 3; ++ky)
#pragma unroll
            for (int kx = 0; kx < 3; ++kx)
#pragma unroll
                for (int c = 0; c < 3; ++c) {
                    float wv = w[(ky * 3 + kx) * 3 + c];
                    acc[0][0] = fmaf(wv, xr[c][ky][kx],         acc[0][0]);
                    acc[0][1] = fmaf(wv, xr[c][ky][kx + 1],     acc[0][1]);
                    acc[1][0] = fmaf(wv, xr[c][ky + 1][kx],     acc[1][0]);
                    acc[1][1] = fmaf(wv, xr[c][ky + 1][kx + 1], acc[1][1]);
                }
        {
            float h00 = acc[0][0], h01 = acc[0][1], h10 = acc[1][0], h11 = acc[1][1];
            float g00 = 0.5f * h00 * (1.0f + erff(h00 * 0.70710678118654752f));
            float g01 = 0.5f * h01 * (1.0f + erff(h01 * 0.70710678118654752f));
            float g10 = 0.5f * h10 * (1.0f + erff(h10 * 0.70710678118654752f));
            float g11 = 0.5f * h11 * (1.0f + erff(h11 * 0.70710678118654752f));
            p0 = fmaf(w2_l[(0 * 96 + e) * 16 + pi00], g00, p0);
            p0 = fmaf(w2_l[(0 * 96 + e) * 16 + pi01], g01, p0);
            p0 = fmaf(w2_l[(0 * 96 + e) * 16 + pi10], g10, p0);
            p0 = fmaf(w2_l[(0 * 96 + e) * 16 + pi11], g11, p0);
            p1 = fmaf(w2_l[(1 * 96 + e) * 16 + pi00], g00, p1);
            p1 = fmaf(w2_l[(1 * 96 + e) * 16 + pi01], g01, p1);
            p1 = fmaf(w2_l[(1 * 96 + e) * 16 + pi10], g10, p1);
            p1 = fmaf(w2_l[(1 * 96 + e) * 16 + pi11], g11, p1);
            p2 = fmaf(w2_l[(2 * 96 + e) * 16 + pi00], g00, p2);
            p2 = fmaf(w2_l[(2 * 96 + e) * 16 + pi01], g01, p2);
            p2 = fmaf(w2_l[(2 * 96 + e) * 16 + pi10], g10, p2);
            p2 = fmaf(w2_l[(2 * 96 + e) * 16 + pi11], g11, p2);
        }
    }

    // reduce over the 4 threads of each patch (consecutive lanes, width 4)
    p0 += __shfl_xor(p0, 1, 4); p0 += __shfl_xor(p0, 2, 4);
    p1 += __shfl_xor(p1, 1, 4); p1 += __shfl_xor(p1, 2, 4);
    p2 += __shfl_xor(p2, 1, 4); p2 += __shfl_xor(p2, 2, 4);

    if (q == 0) {
        int hp = th * 8 + pr, wp = tw * 8 + pc;
        size_t o = ((size_t)b * 3) * 25600 + (size_t)hp * 160 + wp;
        params[o]             = p0 + ph_b2[0];
        params[o + 25600]     = p1 + ph_b2[1];
        params[o + 2 * 25600] = p2 + ph_b2[2];
    }
}

// ---------------------------------------------------------------------------
// Kernel 3: coords + bilinear sample of raw x (3ch) + embed matvec + LayerNorm.
// One wave (64 lanes) per token: lane = sample(0..15)*4 + tap(0..3).
// ---------------------------------------------------------------------------
__device__ __forceinline__ float wred64(float v) {
#pragma unroll
    for (int m = 1; m < 64; m <<= 1) v += __shfl_xor(v, m, 64);
    return v;
}

__global__ __launch_bounds__(256) void token_kernel(
    const float* __restrict__ x,
    const float* __restrict__ params,
    const float* __restrict__ ew,
    const float* __restrict__ eb,
    const float* __restrict__ lnw,
    const float* __restrict__ lnb,
    float* __restrict__ out) {
    int wid = (blockIdx.x << 2) + (threadIdx.x >> 6);
    int lane = threadIdx.x & 63;
    int b = wid / 25600;
    int r = wid - b * 25600;
    int hp = r / 160, wp = r - hp * 160;

    size_t pbase = ((size_t)b * 3) * 25600 + (size_t)hp * 160 + wp;
    float dx = params[pbase];
    float dy = params[pbase + 25600];
    float ls = params[pbase + 2 * 25600];

    float mx = 2.0f * tanhf(dx);
    float my = 2.0f * tanhf(dy);
    float s = expf(tanhf(ls));
    s = fminf(fmaxf(s, 0.5f), 2.0f);
    float half = 2.0f * s;
    float cx = (float)(wp * 4) + 2.0f;
    float cy = (float)(hp * 4) + 2.0f;
    float x1b = fminf(fmaxf(cx + mx - half, 0.f), 639.f);
    float x2b = fminf(fmaxf(cx + mx + half, 0.f), 639.f);
    float y1b = fminf(fmaxf(cy + my - half, 0.f), 639.f);
    float y2b = fminf(fmaxf(cy + my + half, 0.f), 639.f);

    int sidx = lane >> 2, tap = lane & 3;
    int py = sidx >> 2, px = sidx & 3;
    float xs = x1b + (x2b - x1b) * ((float)px * (1.0f / 3.0f));
    float ys = y1b + (y2b - y1b) * ((float)py * (1.0f / 3.0f));
    float x0f = floorf(xs), y0f = floorf(ys);
    float wx = xs - x0f, wy = ys - y0f;
    int x0 = min(max((int)x0f, 0), 639);
    int y0 = min(max((int)y0f, 0), 639);
    int x1i = min(x0 + 1, 639);
    int y1i = min(y0 + 1, 639);
    int xx = (tap & 1) ? x1i : x0;
    int yy = (tap & 2) ? y1i : y0;
    float wgt = ((tap & 1) ? wx : 1.f - wx) * ((tap & 2) ? wy : 1.f - wy);

    const float* xbp = x + (size_t)b * 3 * 409600;
    int off = yy * 640 + xx;
    float a0 = wgt * xbp[off];
    float a1 = wgt * xbp[409600 + off];
    float a2 = wgt * xbp[819200 + off];

    a0 = wred64(a0) * (1.0f / 16.0f);
    a1 = wred64(a1) * (1.0f / 16.0f);
    a2 = wred64(a2) * (1.0f / 16.0f);

    // token channels: d = lane (all), d = 64+lane (lane<32)
    float t1 = eb[lane] + ew[lane * 3] * a0 + ew[lane * 3 + 1] * a1 + ew[lane * 3 + 2] * a2;
    float t2 = 0.f;
    if (lane < 32) {
        int d = 64 + lane;
        t2 = eb[d] + ew[d * 3] * a0 + ew[d * 3 + 1] * a1 + ew[d * 3 + 2] * a2;
    }
    float sum = t1 + ((lane < 32) ? t2 : 0.f);
    float mu = wred64(sum) * (1.0f / 96.0f);
    float d1 = t1 - mu, d2 = t2 - mu;
    float q = d1 * d1 + ((lane < 32) ? d2 * d2 : 0.f);
    float var = wred64(q) * (1.0f / 96.0f);
    float rs = 1.0f / sqrtf(var + 1e-5f);

    size_t ob = ((size_t)b * 25600 + (size_t)hp * 160 + wp) * 96;
    out[ob + lane] = d1 * rs * lnw[lane] + lnb[lane];
    if (lane < 32) {
        int d = 64 + lane;
        out[ob + d] = d2 * rs * lnw[d] + lnb[d];
    }
    if (lane == 0) {
        out[(size_t)4915200 + (size_t)b * 25600 + (size_t)hp * 160 + wp] = s;
    }
}

// ---------------------------------------------------------------------------
extern "C" void kernel_launch(void* const* d_in, const int* in_sizes, int n_in,
                              void* d_out, int out_size, void* d_ws, size_t ws_size,
                              hipStream_t stream) {
    const float* x       = (const float*)d_in[0];
    const float* embed_w = (const float*)d_in[1];
    const float* embed_b = (const float*)d_in[2];
    const float* ph_w1   = (const float*)d_in[3];
    const float* ph_b1   = (const float*)d_in[4];
    const float* ph_w2   = (const float*)d_in[5];
    const float* ph_b2   = (const float*)d_in[6];
    const float* ln_w    = (const float*)d_in[7];
    const float* ln_b    = (const float*)d_in[8];

    float* ws = (float*)d_ws;
    float* W1f      = ws;            // 2592 floats
    float* B1f      = ws + 2592;     // 864
    float* bias_int = ws + 3456;     // 96
    float* params   = ws + 3552;     // 2*3*160*160 = 153600

    fold_kernel<<<14, 256, 0, stream>>>(ph_w1, embed_w, embed_b, ph_b1, W1f, B1f, bias_int);
    params_kernel<<<800, 256, 0, stream>>>(x, W1f, B1f, bias_int, ph_b1, ph_w2, ph_b2, params);
    token_kernel<<<12800, 256, 0, stream>>>(x, params, embed_w, embed_b, ln_w, ln_b, (float*)d_out);
}

// Round 2
// 267.160 us; speedup vs baseline: 1.1192x; 1.1192x over previous
//
#include <hip/hip_runtime.h>
#include <cstdint>
#include <cstddef>

#define IMGW 640
#define HPW  160
#define DCH  96
#define BATCH 2

// ---------------------------------------------------------------------------
// Kernel 1: fold embed (1x1 conv 3->96) into the 3x3 conv ph_w1.
//   W1f (stride 28, padded): W1f[e*28 + (ky*3+kx)*3 + c3]
//   B1f[e*9+k] = sum_c ph_w1[e,c,k] * embed_b[c]
//   bias_int[e] = ph_b1[e] + sum_k B1f[e,k]
// ---------------------------------------------------------------------------
__global__ void fold_kernel(const float* __restrict__ ph_w1,
                            const float* __restrict__ embed_w,
                            const float* __restrict__ embed_b,
                            const float* __restrict__ ph_b1,
                            float* __restrict__ W1f,
                            float* __restrict__ B1f,
                            float* __restrict__ bias_int) {
    int t = blockIdx.x * 256 + threadIdx.x;
    if (t < 96 * 28) {
        int e = t / 28, j = t - e * 28;
        float s = 0.f;
        if (j < 27) {
            int k = j / 3, c3 = j - k * 3;
            for (int c = 0; c < 96; ++c)
                s += ph_w1[e * 864 + c * 9 + k] * embed_w[c * 3 + c3];
        }
        W1f[t] = s;
    } else if (t < 96 * 28 + 864) {
        int i = t - 96 * 28;
        int e = i / 9, k = i - e * 9;
        float s = 0.f;
        for (int c = 0; c < 96; ++c)
            s += ph_w1[e * 864 + c * 9 + k] * embed_b[c];
        B1f[i] = s;
    } else if (t < 96 * 28 + 864 + 96) {
        int e = t - (96 * 28 + 864);
        float s = ph_b1[e];
        for (int c = 0; c < 96; ++c) {
            float bb = embed_b[c];
            const float* w = ph_w1 + e * 864 + c * 9;
            for (int k = 0; k < 9; ++k) s += w[k] * bb;
        }
        bias_int[e] = s;
    }
}

// ---------------------------------------------------------------------------
// Kernel 2: fused conv1(folded,K=27) + GELU + conv2(4x4 s4).
// Block = 8x8 patches = 32x32 px, 256 threads.
// wave = quad position (2x2 px of every patch), lane = patch id.
// => all weight indices wave-uniform => SGPR scalar loads, no weight LDS.
// ---------------------------------------------------------------------------
__global__ __launch_bounds__(256) void params_kernel(
    const float* __restrict__ x,
    const float* __restrict__ W1f,
    const float* __restrict__ B1f,
    const float* __restrict__ bias_int,
    const float* __restrict__ ph_b1,
    const float* __restrict__ ph_w2,
    const float* __restrict__ ph_b2,
    float* __restrict__ params) {
    __shared__ float xs_l[3 * 34 * 34];   // 13872 B x tile + halo
    __shared__ float red[3][4][64];       // 3072 B cross-wave patch reduce

    int bid = blockIdx.x;
    int b = bid / 400;
    int rem = bid - b * 400;
    int th = rem / 20, tw = rem - th * 20;
    int y0 = th * 32, x0 = tw * 32;
    int tid = threadIdx.x;

    const float* xb = x + (size_t)b * 3 * 409600;
    for (int l = tid; l < 3 * 34 * 34; l += 256) {
        int c = l / 1156;
        int r2 = l - c * 1156;
        int rr = r2 / 34, cc = r2 - rr * 34;
        int gy = y0 - 1 + rr, gx = x0 - 1 + cc;
        float v = 0.f;
        if (gy >= 0 && gy < IMGW && gx >= 0 && gx < IMGW)
            v = xb[c * 409600 + gy * 640 + gx];
        xs_l[l] = v;
    }
    __syncthreads();

    int w    = __builtin_amdgcn_readfirstlane(tid >> 6);  // wave id 0..3 (SGPR)
    int lane = tid & 63;
    int pr = lane >> 3, pc = lane & 7;                    // patch row/col
    int qy = w >> 1,   qx = w & 1;                        // quad pos (uniform)
    int ly0 = pr * 4 + qy * 2, lx0 = pc * 4 + qx * 2;     // first pixel (tile coords)
    int pi00 = qy * 8 + qx * 2;                           // uniform conv2 tap base

    // per-thread x window (rows ly0-1..+2 -> halo idx ly0..ly0+3)
    float xr[3][4][4];
#pragma unroll
    for (int c = 0; c < 3; ++c)
#pragma unroll
        for (int i = 0; i < 4; ++i)
#pragma unroll
            for (int j = 0; j < 4; ++j)
                xr[c][i][j] = xs_l[c * 1156 + (ly0 + i) * 34 + (lx0 + j)];

    bool border = (y0 == 0) || (x0 == 0) || (y0 == 608) || (x0 == 608);
    unsigned msk[2][2] = {{0x1ffu, 0x1ffu}, {0x1ffu, 0x1ffu}};
    if (border) {
#pragma unroll
        for (int a = 0; a < 2; ++a)
#pragma unroll
            for (int b2 = 0; b2 < 2; ++b2) {
                int gy = y0 + ly0 + a, gx = x0 + lx0 + b2;
                unsigned m = 0;
                for (int ky = 0; ky < 3; ++ky)
                    for (int kx = 0; kx < 3; ++kx) {
                        int iy = gy + ky - 1, ix = gx + kx - 1;
                        if (iy >= 0 && iy < IMGW && ix >= 0 && ix < IMGW)
                            m |= 1u << (ky * 3 + kx);
                    }
                msk[a][b2] = m;
            }
    }

    float p0 = 0.f, p1 = 0.f, p2 = 0.f;

    for (int e = 0; e < 96; ++e) {
        // folded conv1 weights: uniform address -> s_load_dwordx4 x7
        float wv[28];
        const float4* w4 = reinterpret_cast<const float4*>(W1f + e * 28);
#pragma unroll
        for (int t = 0; t < 7; ++t) {
            float4 v = w4[t];
            wv[4 * t] = v.x; wv[4 * t + 1] = v.y; wv[4 * t + 2] = v.z; wv[4 * t + 3] = v.w;
        }
        float base = bias_int[e];
        float acc[2][2] = {{base, base}, {base, base}};
        if (border) {
#pragma unroll
            for (int a = 0; a < 2; ++a)
#pragma unroll
                for (int b2 = 0; b2 < 2; ++b2) {
                    unsigned m = msk[a][b2];
                    if (m != 0x1ffu) {
                        float bb = ph_b1[e];
                        for (int k = 0; k < 9; ++k)
                            if ((m >> k) & 1u) bb += B1f[e * 9 + k];
                        acc[a][b2] = bb;
                    }
                }
        }
#pragma unroll
        for (int ky = 0; ky < 3; ++ky)
#pragma unroll
            for (int kx = 0; kx < 3; ++kx)
#pragma unroll
                for (int c = 0; c < 3; ++c) {
                    float wvv = wv[(ky * 3 + kx) * 3 + c];
                    acc[0][0] = fmaf(wvv, xr[c][ky][kx],         acc[0][0]);
                    acc[0][1] = fmaf(wvv, xr[c][ky][kx + 1],     acc[0][1]);
                    acc[1][0] = fmaf(wvv, xr[c][ky + 1][kx],     acc[1][0]);
                    acc[1][1] = fmaf(wvv, xr[c][ky + 1][kx + 1], acc[1][1]);
                }
        float g00 = 0.5f * acc[0][0] * (1.0f + erff(acc[0][0] * 0.70710678118654752f));
        float g01 = 0.5f * acc[0][1] * (1.0f + erff(acc[0][1] * 0.70710678118654752f));
        float g10 = 0.5f * acc[1][0] * (1.0f + erff(acc[1][0] * 0.70710678118654752f));
        float g11 = 0.5f * acc[1][1] * (1.0f + erff(acc[1][1] * 0.70710678118654752f));

        // conv2 weights: uniform (pi00 wave-uniform) -> s_load_dwordx2 x6
        const float* w2e = ph_w2 + (size_t)e * 16 + pi00;
        float2 wA = *reinterpret_cast<const float2*>(w2e);               // ch0 taps 00,01
        float2 wAl = *reinterpret_cast<const float2*>(w2e + 4);          // ch0 taps 10,11
        float2 wB = *reinterpret_cast<const float2*>(w2e + 1536);        // ch1
        float2 wBl = *reinterpret_cast<const float2*>(w2e + 1540);
        float2 wC = *reinterpret_cast<const float2*>(w2e + 3072);        // ch2
        float2 wCl = *reinterpret_cast<const float2*>(w2e + 3076);

        p0 = fmaf(wA.x,  g00, p0); p0 = fmaf(wA.y,  g01, p0);
        p0 = fmaf(wAl.x, g10, p0); p0 = fmaf(wAl.y, g11, p0);
        p1 = fmaf(wB.x,  g00, p1); p1 = fmaf(wB.y,  g01, p1);
        p1 = fmaf(wBl.x, g10, p1); p1 = fmaf(wBl.y, g11, p1);
        p2 = fmaf(wC.x,  g00, p2); p2 = fmaf(wC.y,  g01, p2);
        p2 = fmaf(wCl.x, g10, p2); p2 = fmaf(wCl.y, g11, p2);
    }

    red[0][w][lane] = p0;
    red[1][w][lane] = p1;
    red[2][w][lane] = p2;
    __syncthreads();

    if (tid < 192) {
        int ch = tid >> 6, l = tid & 63;
        float s = red[ch][0][l] + red[ch][1][l] + red[ch][2][l] + red[ch][3][l];
        int prr = l >> 3, pcc = l & 7;
        int hp = th * 8 + prr, wp = tw * 8 + pcc;
        size_t o = ((size_t)b * 3 + ch) * 25600 + (size_t)hp * 160 + wp;
        params[o] = s + ph_b2[ch];
    }
}

// ---------------------------------------------------------------------------
// Kernel 3: coords + bilinear sample of raw x (3ch) + embed matvec + LN.
// One wave per token: lane = sample(0..15)*4 + tap(0..3).
// ---------------------------------------------------------------------------
__device__ __forceinline__ float wred64(float v) {
#pragma unroll
    for (int m = 1; m < 64; m <<= 1) v += __shfl_xor(v, m, 64);
    return v;
}

__global__ __launch_bounds__(256) void token_kernel(
    const float* __restrict__ x,
    const float* __restrict__ params,
    const float* __restrict__ ew,
    const float* __restrict__ eb,
    const float* __restrict__ lnw,
    const float* __restrict__ lnb,
    float* __restrict__ out) {
    int wid = (blockIdx.x << 2) + (threadIdx.x >> 6);
    int lane = threadIdx.x & 63;
    int b = wid / 25600;
    int r = wid - b * 25600;
    int hp = r / 160, wp = r - hp * 160;

    size_t pbase = ((size_t)b * 3) * 25600 + (size_t)hp * 160 + wp;
    float dx = params[pbase];
    float dy = params[pbase + 25600];
    float ls = params[pbase + 2 * 25600];

    float mx = 2.0f * tanhf(dx);
    float my = 2.0f * tanhf(dy);
    float s = expf(tanhf(ls));
    s = fminf(fmaxf(s, 0.5f), 2.0f);
    float half = 2.0f * s;
    float cx = (float)(wp * 4) + 2.0f;
    float cy = (float)(hp * 4) + 2.0f;
    float x1b = fminf(fmaxf(cx + mx - half, 0.f), 639.f);
    float x2b = fminf(fmaxf(cx + mx + half, 0.f), 639.f);
    float y1b = fminf(fmaxf(cy + my - half, 0.f), 639.f);
    float y2b = fminf(fmaxf(cy + my + half, 0.f), 639.f);

    int sidx = lane >> 2, tap = lane & 3;
    int py = sidx >> 2, px = sidx & 3;
    float xs = x1b + (x2b - x1b) * ((float)px * (1.0f / 3.0f));
    float ys = y1b + (y2b - y1b) * ((float)py * (1.0f / 3.0f));
    float x0f = floorf(xs), y0f = floorf(ys);
    float wx = xs - x0f, wy = ys - y0f;
    int x0 = min(max((int)x0f, 0), 639);
    int y0 = min(max((int)y0f, 0), 639);
    int x1i = min(x0 + 1, 639);
    int y1i = min(y0 + 1, 639);
    int xx = (tap & 1) ? x1i : x0;
    int yy = (tap & 2) ? y1i : y0;
    float wgt = ((tap & 1) ? wx : 1.f - wx) * ((tap & 2) ? wy : 1.f - wy);

    const float* xbp = x + (size_t)b * 3 * 409600;
    int off = yy * 640 + xx;
    float a0 = wgt * xbp[off];
    float a1 = wgt * xbp[409600 + off];
    float a2 = wgt * xbp[819200 + off];

    a0 = wred64(a0) * (1.0f / 16.0f);
    a1 = wred64(a1) * (1.0f / 16.0f);
    a2 = wred64(a2) * (1.0f / 16.0f);

    float t1 = eb[lane] + ew[lane * 3] * a0 + ew[lane * 3 + 1] * a1 + ew[lane * 3 + 2] * a2;
    float t2 = 0.f;
    if (lane < 32) {
        int d = 64 + lane;
        t2 = eb[d] + ew[d * 3] * a0 + ew[d * 3 + 1] * a1 + ew[d * 3 + 2] * a2;
    }
    float sum = t1 + ((lane < 32) ? t2 : 0.f);
    float mu = wred64(sum) * (1.0f / 96.0f);
    float d1 = t1 - mu, d2 = t2 - mu;
    float q = d1 * d1 + ((lane < 32) ? d2 * d2 : 0.f);
    float var = wred64(q) * (1.0f / 96.0f);
    float rs = 1.0f / sqrtf(var + 1e-5f);

    size_t ob = ((size_t)b * 25600 + (size_t)hp * 160 + wp) * 96;
    out[ob + lane] = d1 * rs * lnw[lane] + lnb[lane];
    if (lane < 32) {
        int d = 64 + lane;
        out[ob + d] = d2 * rs * lnw[d] + lnb[d];
    }
    if (lane == 0) {
        out[(size_t)4915200 + (size_t)b * 25600 + (size_t)hp * 160 + wp] = s;
    }
}

// ---------------------------------------------------------------------------
extern "C" void kernel_launch(void* const* d_in, const int* in_sizes, int n_in,
                              void* d_out, int out_size, void* d_ws, size_t ws_size,
                              hipStream_t stream) {
    const float* x       = (const float*)d_in[0];
    const float* embed_w = (const float*)d_in[1];
    const float* embed_b = (const float*)d_in[2];
    const float* ph_w1   = (const float*)d_in[3];
    const float* ph_b1   = (const float*)d_in[4];
    const float* ph_w2   = (const float*)d_in[5];
    const float* ph_b2   = (const float*)d_in[6];
    const float* ln_w    = (const float*)d_in[7];
    const float* ln_b    = (const float*)d_in[8];

    float* ws = (float*)d_ws;
    float* W1f      = ws;            // 96*28 = 2688 floats (padded stride 28)
    float* B1f      = ws + 2688;     // 864
    float* bias_int = ws + 3552;     // 96
    float* params   = ws + 3648;     // 2*3*160*160 = 153600

    fold_kernel<<<15, 256, 0, stream>>>(ph_w1, embed_w, embed_b, ph_b1, W1f, B1f, bias_int);
    params_kernel<<<800, 256, 0, stream>>>(x, W1f, B1f, bias_int, ph_b1, ph_w2, ph_b2, params);
    token_kernel<<<12800, 256, 0, stream>>>(x, params, embed_w, embed_b, ln_w, ln_b, (float*)d_out);
}

// Round 3
// 169.118 us; speedup vs baseline: 1.7681x; 1.5797x over previous
//
#include <hip/hip_runtime.h>
#include <cstdint>
#include <cstddef>

#define IMGW 640
#define HPW  160
#define DCH  96
#define BATCH 2
#define NG   4      // channel groups
#define CPG  24     // channels per group

// ---------------------------------------------------------------------------
// Kernel 1: fold embed (1x1 conv 3->96) into the 3x3 conv ph_w1.
//   W1f (stride 28, padded): W1f[e*28 + (ky*3+kx)*3 + c3]
//   B1f[e*9+k] = sum_c ph_w1[e,c,k] * embed_b[c]
//   bias_int[e] = ph_b1[e] + sum_k B1f[e,k]
// ---------------------------------------------------------------------------
__global__ void fold_kernel(const float* __restrict__ ph_w1,
                            const float* __restrict__ embed_w,
                            const float* __restrict__ embed_b,
                            const float* __restrict__ ph_b1,
                            float* __restrict__ W1f,
                            float* __restrict__ B1f,
                            float* __restrict__ bias_int) {
    int t = blockIdx.x * 256 + threadIdx.x;
    if (t < 96 * 28) {
        int e = t / 28, j = t - e * 28;
        float s = 0.f;
        if (j < 27) {
            int k = j / 3, c3 = j - k * 3;
            for (int c = 0; c < 96; ++c)
                s += ph_w1[e * 864 + c * 9 + k] * embed_w[c * 3 + c3];
        }
        W1f[t] = s;
    } else if (t < 96 * 28 + 864) {
        int i = t - 96 * 28;
        int e = i / 9, k = i - e * 9;
        float s = 0.f;
        for (int c = 0; c < 96; ++c)
            s += ph_w1[e * 864 + c * 9 + k] * embed_b[c];
        B1f[i] = s;
    } else if (t < 96 * 28 + 864 + 96) {
        int e = t - (96 * 28 + 864);
        float s = ph_b1[e];
        for (int c = 0; c < 96; ++c) {
            float bb = embed_b[c];
            const float* w = ph_w1 + e * 864 + c * 9;
            for (int k = 0; k < 9; ++k) s += w[k] * bb;
        }
        bias_int[e] = s;
    }
}

// ---------------------------------------------------------------------------
// Kernel 2: fused conv1(folded,K=27) + GELU + conv2(4x4 s4), channel-split.
// Block = 8x8 patches = 32x32 px, 256 threads, 24 of 96 channels (g = bid&3).
// wave = quad position, lane = patch id => weight indices wave-uniform (SGPR).
// Writes per-group partial params to ws; token_kernel sums the 4 partials.
// ---------------------------------------------------------------------------
__global__ __launch_bounds__(256) void params_kernel(
    const float* __restrict__ x,
    const float* __restrict__ W1f,
    const float* __restrict__ B1f,
    const float* __restrict__ bias_int,
    const float* __restrict__ ph_b1,
    const float* __restrict__ ph_w2,
    float* __restrict__ part) {
    __shared__ float xs_l[3 * 34 * 34];   // 13872 B x tile + halo
    __shared__ float red[3][4][64];       // 3072 B cross-wave patch reduce

    int bid = blockIdx.x;
    int g = bid & (NG - 1);
    int tile = bid >> 2;
    int b = tile / 400;
    int rem = tile - b * 400;
    int th = rem / 20, tw = rem - th * 20;
    int y0 = th * 32, x0 = tw * 32;
    int tid = threadIdx.x;

    const float* xb = x + (size_t)b * 3 * 409600;
    for (int l = tid; l < 3 * 34 * 34; l += 256) {
        int c = l / 1156;
        int r2 = l - c * 1156;
        int rr = r2 / 34, cc = r2 - rr * 34;
        int gy = y0 - 1 + rr, gx = x0 - 1 + cc;
        float v = 0.f;
        if (gy >= 0 && gy < IMGW && gx >= 0 && gx < IMGW)
            v = xb[c * 409600 + gy * 640 + gx];
        xs_l[l] = v;
    }
    __syncthreads();

    int w    = __builtin_amdgcn_readfirstlane(tid >> 6);  // wave id 0..3 (SGPR)
    int lane = tid & 63;
    int pr = lane >> 3, pc = lane & 7;                    // patch row/col
    int qy = w >> 1,   qx = w & 1;                        // quad pos (uniform)
    int ly0 = pr * 4 + qy * 2, lx0 = pc * 4 + qx * 2;
    int pi00 = qy * 8 + qx * 2;                           // uniform conv2 tap base

    float xr[3][4][4];
#pragma unroll
    for (int c = 0; c < 3; ++c)
#pragma unroll
        for (int i = 0; i < 4; ++i)
#pragma unroll
            for (int j = 0; j < 4; ++j)
                xr[c][i][j] = xs_l[c * 1156 + (ly0 + i) * 34 + (lx0 + j)];

    bool border = (y0 == 0) || (x0 == 0) || (y0 == 608) || (x0 == 608);
    unsigned msk[2][2] = {{0x1ffu, 0x1ffu}, {0x1ffu, 0x1ffu}};
    if (border) {
#pragma unroll
        for (int a = 0; a < 2; ++a)
#pragma unroll
            for (int b2 = 0; b2 < 2; ++b2) {
                int gy = y0 + ly0 + a, gx = x0 + lx0 + b2;
                unsigned m = 0;
                for (int ky = 0; ky < 3; ++ky)
                    for (int kx = 0; kx < 3; ++kx) {
                        int iy = gy + ky - 1, ix = gx + kx - 1;
                        if (iy >= 0 && iy < IMGW && ix >= 0 && ix < IMGW)
                            m |= 1u << (ky * 3 + kx);
                    }
                msk[a][b2] = m;
            }
    }

    float p0 = 0.f, p1 = 0.f, p2 = 0.f;

    int e0 = g * CPG;
    for (int e = e0; e < e0 + CPG; ++e) {
        float wv[28];
        const float4* w4 = reinterpret_cast<const float4*>(W1f + e * 28);
#pragma unroll
        for (int t = 0; t < 7; ++t) {
            float4 v = w4[t];
            wv[4 * t] = v.x; wv[4 * t + 1] = v.y; wv[4 * t + 2] = v.z; wv[4 * t + 3] = v.w;
        }
        float base = bias_int[e];
        float acc[2][2] = {{base, base}, {base, base}};
        if (border) {
#pragma unroll
            for (int a = 0; a < 2; ++a)
#pragma unroll
                for (int b2 = 0; b2 < 2; ++b2) {
                    unsigned m = msk[a][b2];
                    if (m != 0x1ffu) {
                        float bb = ph_b1[e];
                        for (int k = 0; k < 9; ++k)
                            if ((m >> k) & 1u) bb += B1f[e * 9 + k];
                        acc[a][b2] = bb;
                    }
                }
        }
#pragma unroll
        for (int ky = 0; ky < 3; ++ky)
#pragma unroll
            for (int kx = 0; kx < 3; ++kx)
#pragma unroll
                for (int c = 0; c < 3; ++c) {
                    float wvv = wv[(ky * 3 + kx) * 3 + c];
                    acc[0][0] = fmaf(wvv, xr[c][ky][kx],         acc[0][0]);
                    acc[0][1] = fmaf(wvv, xr[c][ky][kx + 1],     acc[0][1]);
                    acc[1][0] = fmaf(wvv, xr[c][ky + 1][kx],     acc[1][0]);
                    acc[1][1] = fmaf(wvv, xr[c][ky + 1][kx + 1], acc[1][1]);
                }
        float g00 = 0.5f * acc[0][0] * (1.0f + erff(acc[0][0] * 0.70710678118654752f));
        float g01 = 0.5f * acc[0][1] * (1.0f + erff(acc[0][1] * 0.70710678118654752f));
        float g10 = 0.5f * acc[1][0] * (1.0f + erff(acc[1][0] * 0.70710678118654752f));
        float g11 = 0.5f * acc[1][1] * (1.0f + erff(acc[1][1] * 0.70710678118654752f));

        const float* w2e = ph_w2 + (size_t)e * 16 + pi00;
        float2 wA  = *reinterpret_cast<const float2*>(w2e);
        float2 wAl = *reinterpret_cast<const float2*>(w2e + 4);
        float2 wB  = *reinterpret_cast<const float2*>(w2e + 1536);
        float2 wBl = *reinterpret_cast<const float2*>(w2e + 1540);
        float2 wC  = *reinterpret_cast<const float2*>(w2e + 3072);
        float2 wCl = *reinterpret_cast<const float2*>(w2e + 3076);

        p0 = fmaf(wA.x,  g00, p0); p0 = fmaf(wA.y,  g01, p0);
        p0 = fmaf(wAl.x, g10, p0); p0 = fmaf(wAl.y, g11, p0);
        p1 = fmaf(wB.x,  g00, p1); p1 = fmaf(wB.y,  g01, p1);
        p1 = fmaf(wBl.x, g10, p1); p1 = fmaf(wBl.y, g11, p1);
        p2 = fmaf(wC.x,  g00, p2); p2 = fmaf(wC.y,  g01, p2);
        p2 = fmaf(wCl.x, g10, p2); p2 = fmaf(wCl.y, g11, p2);
    }

    red[0][w][lane] = p0;
    red[1][w][lane] = p1;
    red[2][w][lane] = p2;
    __syncthreads();

    if (tid < 192) {
        int ch = tid >> 6, l = tid & 63;
        float s = red[ch][0][l] + red[ch][1][l] + red[ch][2][l] + red[ch][3][l];
        int prr = l >> 3, pcc = l & 7;
        int hp = th * 8 + prr, wp = tw * 8 + pcc;
        size_t o = ((size_t)(g * 6 + b * 3 + ch)) * 25600 + (size_t)hp * 160 + wp;
        part[o] = s;
    }
}

// ---------------------------------------------------------------------------
// Kernel 3: sum 4 channel-group partials -> params; coords + bilinear sample
// of raw x (3ch) + embed matvec + LN. One wave per token.
// ---------------------------------------------------------------------------
__device__ __forceinline__ float wred64(float v) {
#pragma unroll
    for (int m = 1; m < 64; m <<= 1) v += __shfl_xor(v, m, 64);
    return v;
}

__global__ __launch_bounds__(256) void token_kernel(
    const float* __restrict__ x,
    const float* __restrict__ part,
    const float* __restrict__ ph_b2,
    const float* __restrict__ ew,
    const float* __restrict__ eb,
    const float* __restrict__ lnw,
    const float* __restrict__ lnb,
    float* __restrict__ out) {
    int wid = (blockIdx.x << 2) + (threadIdx.x >> 6);
    int lane = threadIdx.x & 63;
    int b = wid / 25600;
    int r = wid - b * 25600;
    int hp = r / 160, wp = r - hp * 160;

    size_t idx = (size_t)hp * 160 + wp;
    float dx = ph_b2[0], dy = ph_b2[1], ls = ph_b2[2];
#pragma unroll
    for (int g = 0; g < NG; ++g) {
        const float* pg = part + ((size_t)(g * 6 + b * 3)) * 25600 + idx;
        dx += pg[0];
        dy += pg[25600];
        ls += pg[2 * 25600];
    }

    float mx = 2.0f * tanhf(dx);
    float my = 2.0f * tanhf(dy);
    float s = expf(tanhf(ls));
    s = fminf(fmaxf(s, 0.5f), 2.0f);
    float half = 2.0f * s;
    float cx = (float)(wp * 4) + 2.0f;
    float cy = (float)(hp * 4) + 2.0f;
    float x1b = fminf(fmaxf(cx + mx - half, 0.f), 639.f);
    float x2b = fminf(fmaxf(cx + mx + half, 0.f), 639.f);
    float y1b = fminf(fmaxf(cy + my - half, 0.f), 639.f);
    float y2b = fminf(fmaxf(cy + my + half, 0.f), 639.f);

    int sidx = lane >> 2, tap = lane & 3;
    int py = sidx >> 2, px = sidx & 3;
    float xs = x1b + (x2b - x1b) * ((float)px * (1.0f / 3.0f));
    float ys = y1b + (y2b - y1b) * ((float)py * (1.0f / 3.0f));
    float x0f = floorf(xs), y0f = floorf(ys);
    float wx = xs - x0f, wy = ys - y0f;
    int x0 = min(max((int)x0f, 0), 639);
    int y0 = min(max((int)y0f, 0), 639);
    int x1i = min(x0 + 1, 639);
    int y1i = min(y0 + 1, 639);
    int xx = (tap & 1) ? x1i : x0;
    int yy = (tap & 2) ? y1i : y0;
    float wgt = ((tap & 1) ? wx : 1.f - wx) * ((tap & 2) ? wy : 1.f - wy);

    const float* xbp = x + (size_t)b * 3 * 409600;
    int off = yy * 640 + xx;
    float a0 = wgt * xbp[off];
    float a1 = wgt * xbp[409600 + off];
    float a2 = wgt * xbp[819200 + off];

    a0 = wred64(a0) * (1.0f / 16.0f);
    a1 = wred64(a1) * (1.0f / 16.0f);
    a2 = wred64(a2) * (1.0f / 16.0f);

    float t1 = eb[lane] + ew[lane * 3] * a0 + ew[lane * 3 + 1] * a1 + ew[lane * 3 + 2] * a2;
    float t2 = 0.f;
    if (lane < 32) {
        int d = 64 + lane;
        t2 = eb[d] + ew[d * 3] * a0 + ew[d * 3 + 1] * a1 + ew[d * 3 + 2] * a2;
    }
    float sum = t1 + ((lane < 32) ? t2 : 0.f);
    float mu = wred64(sum) * (1.0f / 96.0f);
    float d1 = t1 - mu, d2 = t2 - mu;
    float q = d1 * d1 + ((lane < 32) ? d2 * d2 : 0.f);
    float var = wred64(q) * (1.0f / 96.0f);
    float rs = 1.0f / sqrtf(var + 1e-5f);

    size_t ob = ((size_t)b * 25600 + idx) * 96;
    out[ob + lane] = d1 * rs * lnw[lane] + lnb[lane];
    if (lane < 32) {
        int d = 64 + lane;
        out[ob + d] = d2 * rs * lnw[d] + lnb[d];
    }
    if (lane == 0) {
        out[(size_t)4915200 + (size_t)b * 25600 + idx] = s;
    }
}

// ---------------------------------------------------------------------------
extern "C" void kernel_launch(void* const* d_in, const int* in_sizes, int n_in,
                              void* d_out, int out_size, void* d_ws, size_t ws_size,
                              hipStream_t stream) {
    const float* x       = (const float*)d_in[0];
    const float* embed_w = (const float*)d_in[1];
    const float* embed_b = (const float*)d_in[2];
    const float* ph_w1   = (const float*)d_in[3];
    const float* ph_b1   = (const float*)d_in[4];
    const float* ph_w2   = (const float*)d_in[5];
    const float* ph_b2   = (const float*)d_in[6];
    const float* ln_w    = (const float*)d_in[7];
    const float* ln_b    = (const float*)d_in[8];

    float* ws = (float*)d_ws;
    float* W1f      = ws;            // 96*28 = 2688 floats
    float* B1f      = ws + 2688;     // 864
    float* bias_int = ws + 3552;     // 96
    float* part     = ws + 3648;     // NG*2*3*25600 = 614400 floats

    fold_kernel<<<15, 256, 0, stream>>>(ph_w1, embed_w, embed_b, ph_b1, W1f, B1f, bias_int);
    params_kernel<<<800 * NG, 256, 0, stream>>>(x, W1f, B1f, bias_int, ph_b1, ph_w2, part);
    token_kernel<<<12800, 256, 0, stream>>>(x, part, ph_b2, embed_w, embed_b, ln_w, ln_b, (float*)d_out);
}